// Round 7
// baseline (867.193 us; speedup 1.0000x reference)
//
#include <hip/hip_runtime.h>
#include <hip/hip_bf16.h>
#include <stdint.h>

// Problem dims
#define Bn 16384
#define Cn 512
#define Dn 512
#define Hn 1024

// a = 1 - 0.95^32 (closed-form Langevin: u32 = -a*e + Z)
#define A32 0.80628851f

typedef __attribute__((ext_vector_type(8))) short bf16x8;   // 8 bf16 (4 VGPRs)
typedef __attribute__((ext_vector_type(4))) float f32x4;    // MFMA accum

// f32 -> bf16 RTNE (manual; inputs are finite)
__device__ __forceinline__ ushort f2bf(float f) {
  uint32_t u = __float_as_uint(f);
  return (ushort)((u + 0x7fffu + ((u >> 16) & 1u)) >> 16);
}
__device__ __forceinline__ float b2f(ushort u) {
  return __uint_as_float((uint32_t)u << 16);
}

// ---------------------------------------------------------------------------
// JAX threefry2x32 (20 rounds), PARTITIONABLE semantics (verified round 4)
// ---------------------------------------------------------------------------
__device__ __forceinline__ uint32_t rotl32(uint32_t v, int s) {
  return __builtin_rotateleft32(v, (uint32_t)s);
}

__device__ __forceinline__ void threefry2x32(uint32_t k0, uint32_t k1,
                                             uint32_t x0, uint32_t x1,
                                             uint32_t& o0, uint32_t& o1) {
  const uint32_t k2 = k0 ^ k1 ^ 0x1BD11BDAu;
  x0 += k0; x1 += k1;
#define TFR(r) { x0 += x1; x1 = rotl32(x1, (r)); x1 ^= x0; }
  TFR(13) TFR(15) TFR(26) TFR(6)   x0 += k1; x1 += k2 + 1u;
  TFR(17) TFR(29) TFR(16) TFR(24)  x0 += k2; x1 += k0 + 2u;
  TFR(13) TFR(15) TFR(26) TFR(6)   x0 += k0; x1 += k1 + 3u;
  TFR(17) TFR(29) TFR(16) TFR(24)  x0 += k1; x1 += k2 + 4u;
  TFR(13) TFR(15) TFR(26) TFR(6)   x0 += k2; x1 += k0 + 5u;
#undef TFR
  o0 = x0; o1 = x1;
}

// Exact (branchy) bits->normal — used by the static mask path (unchanged).
__device__ __forceinline__ float bits_to_normal(uint32_t bits) {
  float f = __uint_as_float((bits >> 9) | 0x3f800000u) - 1.0f;
  float x = f * 2.0f - 0x1.fffffep-1f;
  float w = -__logf(1.0f - x * x);
  float p;
  if (w < 5.0f) {
    w -= 2.5f;
    p =            2.81022636e-08f;
    p = fmaf(p, w, 3.43273939e-07f);
    p = fmaf(p, w, -3.5233877e-06f);
    p = fmaf(p, w, -4.39150654e-06f);
    p = fmaf(p, w, 0.00021858087f);
    p = fmaf(p, w, -0.00125372503f);
    p = fmaf(p, w, -0.00417768164f);
    p = fmaf(p, w, 0.246640727f);
    p = fmaf(p, w, 1.50140941f);
  } else {
    w = sqrtf(w) - 3.0f;
    p =            -0.000200214257f;
    p = fmaf(p, w, 0.000100950558f);
    p = fmaf(p, w, 0.00134934322f);
    p = fmaf(p, w, -0.00367342844f);
    p = fmaf(p, w, 0.00573950773f);
    p = fmaf(p, w, -0.0076224613f);
    p = fmaf(p, w, 0.00943887047f);
    p = fmaf(p, w, 1.00167406f);
    p = fmaf(p, w, 2.83297682f);
  }
  return 0x1.6a09e6p+0f * (p * x);
}

// Dieted branchless normal (tail capped at w=5; error << bf16 visibility).
// Returns p*x with sqrt(2) NOT applied (folded into the chain constant).
__device__ __forceinline__ float bits_to_px(uint32_t bits) {
  float f = __uint_as_float((bits >> 9) | 0x3f800000u) - 1.0f;
  float x = f * 2.0f - 0x1.fffffep-1f;
  float w = -__logf(fmaf(-x, x, 1.0f));
  w = fminf(w, 5.0f) - 2.5f;
  float p =      2.81022636e-08f;
  p = fmaf(p, w, 3.43273939e-07f);
  p = fmaf(p, w, -3.5233877e-06f);
  p = fmaf(p, w, -4.39150654e-06f);
  p = fmaf(p, w, 0.00021858087f);
  p = fmaf(p, w, -0.00125372503f);
  p = fmaf(p, w, -0.00417768164f);
  p = fmaf(p, w, 0.246640727f);
  p = fmaf(p, w, 1.50140941f);
  return p * x;
}

// keys[0..63] = static-mask step keys; keys[64..127] = dynamic-gate step keys
__global__ void k_setup_keys(uint32_t* __restrict__ keys) {
  if (threadIdx.x != 0 || blockIdx.x != 0) return;
  uint32_t k1w0, k1w1, k2w0, k2w1;
  threefry2x32(0u, 42u, 0u, 0u, k1w0, k1w1);
  threefry2x32(0u, 42u, 0u, 1u, k2w0, k2w1);
  for (uint32_t t = 0; t < 32; ++t) {
    uint32_t w0, w1;
    threefry2x32(k1w0, k1w1, 0u, t, w0, w1);
    keys[2 * t] = w0; keys[2 * t + 1] = w1;
    threefry2x32(k2w0, k2w1, 0u, t, w0, w1);
    keys[64 + 2 * t] = w0; keys[64 + 2 * t + 1] = w1;
  }
}

// out[n*KO + k] = bf16(in[k*NO + n]);  in is [KO][NO], out is [NO][KO]
__global__ __launch_bounds__(256) void k_transpose_cvt(
    const float* __restrict__ in, ushort* __restrict__ out, int NO, int KO) {
  int o = blockIdx.x * 256 + threadIdx.x;
  int n = o / KO, k = o % KO;
  out[o] = f2bf(in[(size_t)k * NO + n]);
}

// ---------------------------------------------------------------------------
// Mega-kernel K1 roles
// ---------------------------------------------------------------------------

// GEMM tile: Out[m0..+128][n0..+128] = bf16(relu(x@WT^T + bias)), x is f32.
// K = Dn = 512, out stride Hn.
__device__ __forceinline__ void gemm_tile_xf32(
    const float* __restrict__ A, const ushort* __restrict__ WT,
    const float* __restrict__ bias, ushort* __restrict__ Out, int g,
    ushort As[128][40], ushort Bs[128][40]) {
  const int n0 = (g & 7) * 128, m0 = (g >> 3) * 128;
  const int t = threadIdx.x;
  const int srow = t >> 1, skb = (t & 1) << 4;
  const float*  Ap = A  + (size_t)(m0 + srow) * Dn + skb;
  const ushort* Bp = WT + (size_t)(n0 + srow) * Dn + skb;
  const int wave = t >> 6, lane = t & 63;
  const int wm = (wave >> 1) << 6, wn = (wave & 1) << 6;
  const int quad = lane >> 4, l15 = lane & 15;

  f32x4 acc[4][4] = {};
  for (int k0 = 0; k0 < Dn; k0 += 32) {
    float4 a0 = *(const float4*)(Ap + k0);
    float4 a1 = *(const float4*)(Ap + k0 + 4);
    float4 a2 = *(const float4*)(Ap + k0 + 8);
    float4 a3 = *(const float4*)(Ap + k0 + 12);
    uint4 b0 = *(const uint4*)(Bp + k0);
    uint4 b1 = *(const uint4*)(Bp + k0 + 8);
    *(ushort4*)&As[srow][skb + 0]  = make_ushort4(f2bf(a0.x), f2bf(a0.y), f2bf(a0.z), f2bf(a0.w));
    *(ushort4*)&As[srow][skb + 4]  = make_ushort4(f2bf(a1.x), f2bf(a1.y), f2bf(a1.z), f2bf(a1.w));
    *(ushort4*)&As[srow][skb + 8]  = make_ushort4(f2bf(a2.x), f2bf(a2.y), f2bf(a2.z), f2bf(a2.w));
    *(ushort4*)&As[srow][skb + 12] = make_ushort4(f2bf(a3.x), f2bf(a3.y), f2bf(a3.z), f2bf(a3.w));
    *(uint4*)&Bs[srow][skb] = b0;
    *(uint4*)&Bs[srow][skb + 8] = b1;
    __syncthreads();
    bf16x8 af[4], bfr[4];
#pragma unroll
    for (int i = 0; i < 4; ++i) {
      af[i] = *(const bf16x8*)&As[wm + i * 16 + l15][quad * 8];
      bfr[i] = *(const bf16x8*)&Bs[wn + i * 16 + l15][quad * 8];
    }
#pragma unroll
    for (int i = 0; i < 4; ++i)
#pragma unroll
      for (int j = 0; j < 4; ++j)
        acc[i][j] = __builtin_amdgcn_mfma_f32_16x16x32_bf16(af[i], bfr[j],
                                                            acc[i][j], 0, 0, 0);
    __syncthreads();
  }
#pragma unroll
  for (int i = 0; i < 4; ++i)
#pragma unroll
    for (int j = 0; j < 4; ++j) {
      const int col = n0 + wn + j * 16 + l15;
      const float bv = bias[col];
#pragma unroll
      for (int r = 0; r < 4; ++r) {
        const int row = m0 + wm + i * 16 + quad * 4 + r;
        Out[(size_t)row * Hn + col] = f2bf(fmaxf(acc[i][j][r] + bv, 0.0f));
      }
    }
}

// Static mask block (exact round-6 path): compsT[j] = |vc|*sigmoid(-u(e_sp))
__device__ __forceinline__ void smask_block(
    const float* __restrict__ vc, const float* __restrict__ e_sp,
    const uint32_t* __restrict__ keys, ushort* __restrict__ compsT, int g) {
  uint32_t j = (uint32_t)g * 256 + threadIdx.x;  // j = d*C + c
  uint32_t c = j & (Cn - 1), d = j >> 9;
  uint32_t ridx = c * Dn + d;
  float e = e_sp[ridx];
  float u = 0.0f;
#pragma unroll 1
  for (int t = 0; t < 32; ++t) {
    uint32_t o0, o1;
    threefry2x32(keys[2 * t], keys[2 * t + 1], 0u, ridx, o0, o1);
    float n = bits_to_normal(o0 ^ o1);
    u = (u - 0.05f * (u + e)) + 0.1f * n;
  }
  float gt = 1.0f / (1.0f + __expf(u));
  compsT[j] = f2bf(fabsf(vc[ridx]) * gt);
}

// Z block: Z[j] for 4 elements; Z = sum 0.95^(31-t) * 0.1 * n_t  (e-free)
__device__ __forceinline__ void zdyn_block(
    const uint32_t* __restrict__ keys, ushort* __restrict__ Z, uint32_t rb) {
  const uint32_t j0 = (rb * 256u + threadIdx.x) * 4u;
  float z0 = 0.0f, z1 = 0.0f, z2 = 0.0f, z3 = 0.0f;
#pragma unroll 4
  for (int t = 0; t < 32; ++t) {
    const uint32_t K0 = keys[2 * t], K1 = keys[2 * t + 1];
    uint32_t a0, b0, a1, b1, a2, b2, a3, b3;
    threefry2x32(K0, K1, 0u, j0 + 0u, a0, b0);
    threefry2x32(K0, K1, 0u, j0 + 1u, a1, b1);
    threefry2x32(K0, K1, 0u, j0 + 2u, a2, b2);
    threefry2x32(K0, K1, 0u, j0 + 3u, a3, b3);
    // 0.1 * sqrt(2) folded: n-contribution = px * 0.14142135
    z0 = fmaf(0.95f, z0, bits_to_px(a0 ^ b0) * 0.14142135f);
    z1 = fmaf(0.95f, z1, bits_to_px(a1 ^ b1) * 0.14142135f);
    z2 = fmaf(0.95f, z2, bits_to_px(a2 ^ b2) * 0.14142135f);
    z3 = fmaf(0.95f, z3, bits_to_px(a3 ^ b3) * 0.14142135f);
  }
  *(ushort4*)(Z + j0) = make_ushort4(f2bf(z0), f2bf(z1), f2bf(z2), f2bf(z3));
}

// K1: 11264 blocks = 1024 groups x 11: pos 0=G1, 1=G3, 2=SMASK, 3..10=Zdyn
__global__ __launch_bounds__(256) void k_mega(
    const float* __restrict__ x,
    const ushort* __restrict__ W1eT, const float* __restrict__ b1e, ushort* __restrict__ h,
    const ushort* __restrict__ W1rT, const float* __restrict__ b1r, ushort* __restrict__ hr,
    const float* __restrict__ vc, const float* __restrict__ e_sp,
    const uint32_t* __restrict__ keys, ushort* __restrict__ compsT,
    ushort* __restrict__ Zdyn) {
  __shared__ ushort As[128][40];
  __shared__ ushort Bs[128][40];
  const uint32_t bx = blockIdx.x;
  const uint32_t group = bx / 11u, pos = bx % 11u;
  if (pos == 0u)
    gemm_tile_xf32(x, W1eT, b1e, h, (int)group, As, Bs);
  else if (pos == 1u)
    gemm_tile_xf32(x, W1rT, b1r, hr, (int)group, As, Bs);
  else if (pos == 2u)
    smask_block(vc, e_sp, keys, compsT, (int)group);
  else
    zdyn_block(keys + 64, Zdyn, group * 8u + (pos - 3u));
}

// ---------------------------------------------------------------------------
// K2: double GEMM + gate.  Tile [128 x 128] of [Bn x Cn].
//   pass1: e = h @ W2eT + b2e;  g = sigmoid(A32*e - Z)
//   pass2: conc = (hr @ W2rT + b2r) * g  -> bf16 into Zconc (aliases Zdyn)
// ---------------------------------------------------------------------------
__global__ __launch_bounds__(256) void k_dgemm(
    const ushort* __restrict__ h, const ushort* __restrict__ W2eT,
    const float* __restrict__ b2e,
    const ushort* __restrict__ hr, const ushort* __restrict__ W2rT,
    const float* __restrict__ b2r,
    ushort* __restrict__ Zconc) {
  __shared__ ushort As[128][40];
  __shared__ ushort Bs[128][40];
  const int t = threadIdx.x;
  const int m0 = blockIdx.y * 128, n0 = blockIdx.x * 128;
  const int srow = t >> 1, skb = (t & 1) << 4;
  const int wave = t >> 6, lane = t & 63;
  const int wm = (wave >> 1) << 6, wn = (wave & 1) << 6;
  const int quad = lane >> 4, l15 = lane & 15;

  // ---- pass 1: e = h @ W2eT ----
  const ushort* Ap = h    + (size_t)(m0 + srow) * Hn + skb;
  const ushort* Bp = W2eT + (size_t)(n0 + srow) * Hn + skb;
  f32x4 acc[4][4] = {};
  for (int k0 = 0; k0 < Hn; k0 += 32) {
    uint4 a0 = *(const uint4*)(Ap + k0);
    uint4 a1 = *(const uint4*)(Ap + k0 + 8);
    uint4 b0 = *(const uint4*)(Bp + k0);
    uint4 b1 = *(const uint4*)(Bp + k0 + 8);
    *(uint4*)&As[srow][skb] = a0; *(uint4*)&As[srow][skb + 8] = a1;
    *(uint4*)&Bs[srow][skb] = b0; *(uint4*)&Bs[srow][skb + 8] = b1;
    __syncthreads();
    bf16x8 af[4], bfr[4];
#pragma unroll
    for (int i = 0; i < 4; ++i) {
      af[i] = *(const bf16x8*)&As[wm + i * 16 + l15][quad * 8];
      bfr[i] = *(const bf16x8*)&Bs[wn + i * 16 + l15][quad * 8];
    }
#pragma unroll
    for (int i = 0; i < 4; ++i)
#pragma unroll
      for (int j = 0; j < 4; ++j)
        acc[i][j] = __builtin_amdgcn_mfma_f32_16x16x32_bf16(af[i], bfr[j],
                                                            acc[i][j], 0, 0, 0);
    __syncthreads();
  }
  // gate in registers
  float g[4][4][4];
#pragma unroll
  for (int i = 0; i < 4; ++i)
#pragma unroll
    for (int j = 0; j < 4; ++j) {
      const int col = n0 + wn + j * 16 + l15;
      const float bv = b2e[col];
#pragma unroll
      for (int r = 0; r < 4; ++r) {
        const int row = m0 + wm + i * 16 + quad * 4 + r;
        float e = acc[i][j][r] + bv;
        float z = b2f(Zconc[(size_t)row * Cn + col]);
        g[i][j][r] = 1.0f / (1.0f + __expf(z - A32 * e));
        acc[i][j][r] = 0.0f;
      }
    }
  // ---- pass 2: r = hr @ W2rT ----
  Ap = hr   + (size_t)(m0 + srow) * Hn + skb;
  Bp = W2rT + (size_t)(n0 + srow) * Hn + skb;
  for (int k0 = 0; k0 < Hn; k0 += 32) {
    uint4 a0 = *(const uint4*)(Ap + k0);
    uint4 a1 = *(const uint4*)(Ap + k0 + 8);
    uint4 b0 = *(const uint4*)(Bp + k0);
    uint4 b1 = *(const uint4*)(Bp + k0 + 8);
    __syncthreads();  // ensure all pass-1/prev-iter LDS reads are done
    *(uint4*)&As[srow][skb] = a0; *(uint4*)&As[srow][skb + 8] = a1;
    *(uint4*)&Bs[srow][skb] = b0; *(uint4*)&Bs[srow][skb + 8] = b1;
    __syncthreads();
    bf16x8 af[4], bfr[4];
#pragma unroll
    for (int i = 0; i < 4; ++i) {
      af[i] = *(const bf16x8*)&As[wm + i * 16 + l15][quad * 8];
      bfr[i] = *(const bf16x8*)&Bs[wn + i * 16 + l15][quad * 8];
    }
#pragma unroll
    for (int i = 0; i < 4; ++i)
#pragma unroll
      for (int j = 0; j < 4; ++j)
        acc[i][j] = __builtin_amdgcn_mfma_f32_16x16x32_bf16(af[i], bfr[j],
                                                            acc[i][j], 0, 0, 0);
  }
#pragma unroll
  for (int i = 0; i < 4; ++i)
#pragma unroll
    for (int j = 0; j < 4; ++j) {
      const int col = n0 + wn + j * 16 + l15;
      const float bv = b2r[col];
#pragma unroll
      for (int r = 0; r < 4; ++r) {
        const int row = m0 + wm + i * 16 + quad * 4 + r;
        Zconc[(size_t)row * Cn + col] = f2bf((acc[i][j][r] + bv) * g[i][j][r]);
      }
    }
}

// ---------------------------------------------------------------------------
// K3: out = conc @ comps  (A bf16 [Bn][Cn], WT = compsT [Dn][Cn], f32 out)
// ---------------------------------------------------------------------------
__global__ __launch_bounds__(256) void k_gemm_out(
    const ushort* __restrict__ A, const ushort* __restrict__ WT,
    float* __restrict__ Out) {
  __shared__ ushort As[128][40];
  __shared__ ushort Bs[128][40];
  const int t = threadIdx.x;
  const int m0 = blockIdx.y * 128, n0 = blockIdx.x * 128;
  const int srow = t >> 1, skb = (t & 1) << 4;
  const ushort* Ap = A  + (size_t)(m0 + srow) * Cn + skb;
  const ushort* Bp = WT + (size_t)(n0 + srow) * Cn + skb;
  const int wave = t >> 6, lane = t & 63;
  const int wm = (wave >> 1) << 6, wn = (wave & 1) << 6;
  const int quad = lane >> 4, l15 = lane & 15;

  f32x4 acc[4][4] = {};
  for (int k0 = 0; k0 < Cn; k0 += 32) {
    uint4 a0 = *(const uint4*)(Ap + k0);
    uint4 a1 = *(const uint4*)(Ap + k0 + 8);
    uint4 b0 = *(const uint4*)(Bp + k0);
    uint4 b1 = *(const uint4*)(Bp + k0 + 8);
    *(uint4*)&As[srow][skb] = a0; *(uint4*)&As[srow][skb + 8] = a1;
    *(uint4*)&Bs[srow][skb] = b0; *(uint4*)&Bs[srow][skb + 8] = b1;
    __syncthreads();
    bf16x8 af[4], bfr[4];
#pragma unroll
    for (int i = 0; i < 4; ++i) {
      af[i] = *(const bf16x8*)&As[wm + i * 16 + l15][quad * 8];
      bfr[i] = *(const bf16x8*)&Bs[wn + i * 16 + l15][quad * 8];
    }
#pragma unroll
    for (int i = 0; i < 4; ++i)
#pragma unroll
      for (int j = 0; j < 4; ++j)
        acc[i][j] = __builtin_amdgcn_mfma_f32_16x16x32_bf16(af[i], bfr[j],
                                                            acc[i][j], 0, 0, 0);
    __syncthreads();
  }
#pragma unroll
  for (int i = 0; i < 4; ++i)
#pragma unroll
    for (int j = 0; j < 4; ++j) {
      const int col = n0 + wn + j * 16 + l15;
#pragma unroll
      for (int r = 0; r < 4; ++r) {
        const int row = m0 + wm + i * 16 + quad * 4 + r;
        Out[(size_t)row * Dn + col] = acc[i][j][r];
      }
    }
}

// ---------------------------------------------------------------------------
extern "C" void kernel_launch(void* const* d_in, const int* in_sizes, int n_in,
                              void* d_out, int out_size, void* d_ws, size_t ws_size,
                              hipStream_t stream) {
  const float* x    = (const float*)d_in[0];
  const float* vc   = (const float*)d_in[1];
  const float* e_sp = (const float*)d_in[2];
  const float* W1e  = (const float*)d_in[3];
  const float* b1e  = (const float*)d_in[4];
  const float* W2e  = (const float*)d_in[5];
  const float* b2e  = (const float*)d_in[6];
  const float* W1r  = (const float*)d_in[7];
  const float* b1r  = (const float*)d_in[8];
  const float* W2r  = (const float*)d_in[9];
  const float* b2r  = (const float*)d_in[10];
  float* out = (float*)d_out;

  // Workspace (ends at 88 MiB, same high-water as round 5):
  //   0       keys (512 B)
  //   4096    W1eT | +1M W2eT | +2M W1rT | +3M W2rT  (bf16 transposed)
  //   +4M     compsT [D][C] bf16 (0.5 MiB)
  //   8M      Zdyn [B][C] bf16 (16 MiB) -> aliased as conc after K2
  //   24M     h  [B][H] bf16 (32 MiB)
  //   56M     hr [B][H] bf16 (32 MiB)
  char* ws = (char*)d_ws;
  uint32_t* keys = (uint32_t*)ws;
  ushort* W1eT   = (ushort*)(ws + (1u << 12));
  ushort* W2eT   = (ushort*)(ws + (1u << 12) + (1u << 20));
  ushort* W1rT   = (ushort*)(ws + (1u << 12) + (2u << 20));
  ushort* W2rT   = (ushort*)(ws + (1u << 12) + (3u << 20));
  ushort* compsT = (ushort*)(ws + (1u << 12) + (4u << 20));
  ushort* Zdyn   = (ushort*)(ws + (8u << 20));   // then conc
  ushort* h_bf   = (ushort*)(ws + (24u << 20));
  ushort* hr_bf  = (ushort*)(ws + (56u << 20));

  // 1. keys + weight transposes
  k_setup_keys<<<1, 64, 0, stream>>>(keys);
  k_transpose_cvt<<<(Dn * Hn) / 256, 256, 0, stream>>>(W1e, W1eT, Hn, Dn);
  k_transpose_cvt<<<(Hn * Cn) / 256, 256, 0, stream>>>(W2e, W2eT, Cn, Hn);
  k_transpose_cvt<<<(Dn * Hn) / 256, 256, 0, stream>>>(W1r, W1rT, Hn, Dn);
  k_transpose_cvt<<<(Hn * Cn) / 256, 256, 0, stream>>>(W2r, W2rT, Cn, Hn);
  // 2. mega-kernel: G1(h) + G3(hr) + static mask + Zdyn, co-scheduled
  k_mega<<<11264, 256, 0, stream>>>(x, W1eT, b1e, h_bf, W1rT, b1r, hr_bf,
                                    vc, e_sp, keys, compsT, Zdyn);
  // 3. double GEMM: e -> gate -> conc (conc overwrites Zdyn tile-local)
  k_dgemm<<<dim3(Cn / 128, Bn / 128), 256, 0, stream>>>(
      h_bf, W2eT, b2e, hr_bf, W2rT, b2r, Zdyn);
  // 4. out = conc @ comps
  k_gemm_out<<<dim3(Dn / 128, Bn / 128), 256, 0, stream>>>(Zdyn, compsT, out);
}

// Round 8
// 852.298 us; speedup vs baseline: 1.0175x; 1.0175x over previous
//
#include <hip/hip_runtime.h>
#include <hip/hip_bf16.h>
#include <stdint.h>

// Problem dims
#define Bn 16384
#define Cn 512
#define Dn 512
#define Hn 1024

// a = 1 - 0.95^32 (closed-form Langevin: u32 = -a*e + Z)
#define A32 0.80628851f

typedef __attribute__((ext_vector_type(8))) short bf16x8;   // 8 bf16 (4 VGPRs)
typedef __attribute__((ext_vector_type(4))) float f32x4;    // MFMA accum
typedef __attribute__((ext_vector_type(2))) float f32x2;    // packed fp32 pair

// f32 -> bf16 RTNE (manual; inputs are finite)
__device__ __forceinline__ ushort f2bf(float f) {
  uint32_t u = __float_as_uint(f);
  return (ushort)((u + 0x7fffu + ((u >> 16) & 1u)) >> 16);
}
__device__ __forceinline__ float b2f(ushort u) {
  return __uint_as_float((uint32_t)u << 16);
}

// ---------------------------------------------------------------------------
// JAX threefry2x32 (20 rounds), PARTITIONABLE semantics (verified round 4)
// ---------------------------------------------------------------------------
__device__ __forceinline__ uint32_t rotl32(uint32_t v, int s) {
  return __builtin_rotateleft32(v, (uint32_t)s);
}

__device__ __forceinline__ void threefry2x32(uint32_t k0, uint32_t k1,
                                             uint32_t x0, uint32_t x1,
                                             uint32_t& o0, uint32_t& o1) {
  const uint32_t k2 = k0 ^ k1 ^ 0x1BD11BDAu;
  x0 += k0; x1 += k1;
#define TFR(r) { x0 += x1; x1 = rotl32(x1, (r)); x1 ^= x0; }
  TFR(13) TFR(15) TFR(26) TFR(6)   x0 += k1; x1 += k2 + 1u;
  TFR(17) TFR(29) TFR(16) TFR(24)  x0 += k2; x1 += k0 + 2u;
  TFR(13) TFR(15) TFR(26) TFR(6)   x0 += k0; x1 += k1 + 3u;
  TFR(17) TFR(29) TFR(16) TFR(24)  x0 += k1; x1 += k2 + 4u;
  TFR(13) TFR(15) TFR(26) TFR(6)   x0 += k2; x1 += k0 + 5u;
#undef TFR
  o0 = x0; o1 = x1;
}

// Exact (branchy) bits->normal — static-mask path only.
__device__ __forceinline__ float bits_to_normal(uint32_t bits) {
  float f = __uint_as_float((bits >> 9) | 0x3f800000u) - 1.0f;
  float x = f * 2.0f - 0x1.fffffep-1f;
  float w = -__logf(1.0f - x * x);
  float p;
  if (w < 5.0f) {
    w -= 2.5f;
    p =            2.81022636e-08f;
    p = fmaf(p, w, 3.43273939e-07f);
    p = fmaf(p, w, -3.5233877e-06f);
    p = fmaf(p, w, -4.39150654e-06f);
    p = fmaf(p, w, 0.00021858087f);
    p = fmaf(p, w, -0.00125372503f);
    p = fmaf(p, w, -0.00417768164f);
    p = fmaf(p, w, 0.246640727f);
    p = fmaf(p, w, 1.50140941f);
  } else {
    w = sqrtf(w) - 3.0f;
    p =            -0.000200214257f;
    p = fmaf(p, w, 0.000100950558f);
    p = fmaf(p, w, 0.00134934322f);
    p = fmaf(p, w, -0.00367342844f);
    p = fmaf(p, w, 0.00573950773f);
    p = fmaf(p, w, -0.0076224613f);
    p = fmaf(p, w, 0.00943887047f);
    p = fmaf(p, w, 1.00167406f);
    p = fmaf(p, w, 2.83297682f);
  }
  return 0x1.6a09e6p+0f * (p * x);
}

// keys[0..63] = static-mask step keys; keys[64..127] = dynamic-gate step keys
__global__ void k_setup_keys(uint32_t* __restrict__ keys) {
  if (threadIdx.x != 0 || blockIdx.x != 0) return;
  uint32_t k1w0, k1w1, k2w0, k2w1;
  threefry2x32(0u, 42u, 0u, 0u, k1w0, k1w1);
  threefry2x32(0u, 42u, 0u, 1u, k2w0, k2w1);
  for (uint32_t t = 0; t < 32; ++t) {
    uint32_t w0, w1;
    threefry2x32(k1w0, k1w1, 0u, t, w0, w1);
    keys[2 * t] = w0; keys[2 * t + 1] = w1;
    threefry2x32(k2w0, k2w1, 0u, t, w0, w1);
    keys[64 + 2 * t] = w0; keys[64 + 2 * t + 1] = w1;
  }
}

// out[n*KO + k] = bf16(in[k*NO + n])
__global__ __launch_bounds__(256) void k_transpose_cvt(
    const float* __restrict__ in, ushort* __restrict__ out, int NO, int KO) {
  int o = blockIdx.x * 256 + threadIdx.x;
  int n = o / KO, k = o % KO;
  out[o] = f2bf(in[(size_t)k * NO + n]);
}

// x (f32) -> bf16, 4 elems/thread
__global__ __launch_bounds__(256) void k_cvt_x(const float* __restrict__ in,
                                               ushort* __restrict__ out) {
  int i = (blockIdx.x * 256 + threadIdx.x) * 4;
  float4 v = *(const float4*)(in + i);
  *(ushort4*)(out + i) = make_ushort4(f2bf(v.x), f2bf(v.y), f2bf(v.z), f2bf(v.w));
}

// ---------------------------------------------------------------------------
// Mega-kernel roles
// ---------------------------------------------------------------------------

// GEMM tile (bf16 A): Out[128x128 tile] = bf16(relu(A @ WT^T + bias)).
// A [Bn][Dn] bf16, WT [Hn][Dn] bf16, out stride Hn.
__device__ __forceinline__ void gemm_tile_bf(
    const ushort* __restrict__ A, const ushort* __restrict__ WT,
    const float* __restrict__ bias, ushort* __restrict__ Out, int g,
    ushort As[128][40], ushort Bs[128][40]) {
  const int n0 = (g & 7) * 128, m0 = (g >> 3) * 128;
  const int t = threadIdx.x;
  const int srow = t >> 1, skb = (t & 1) << 4;
  const ushort* Ap = A  + (size_t)(m0 + srow) * Dn + skb;
  const ushort* Bp = WT + (size_t)(n0 + srow) * Dn + skb;
  const int wave = t >> 6, lane = t & 63;
  const int wm = (wave >> 1) << 6, wn = (wave & 1) << 6;
  const int quad = lane >> 4, l15 = lane & 15;

  f32x4 acc[4][4] = {};
  for (int k0 = 0; k0 < Dn; k0 += 32) {
    uint4 a0 = *(const uint4*)(Ap + k0);
    uint4 a1 = *(const uint4*)(Ap + k0 + 8);
    uint4 b0 = *(const uint4*)(Bp + k0);
    uint4 b1 = *(const uint4*)(Bp + k0 + 8);
    *(uint4*)&As[srow][skb] = a0; *(uint4*)&As[srow][skb + 8] = a1;
    *(uint4*)&Bs[srow][skb] = b0; *(uint4*)&Bs[srow][skb + 8] = b1;
    __syncthreads();
    bf16x8 af[4], bfr[4];
#pragma unroll
    for (int i = 0; i < 4; ++i) {
      af[i] = *(const bf16x8*)&As[wm + i * 16 + l15][quad * 8];
      bfr[i] = *(const bf16x8*)&Bs[wn + i * 16 + l15][quad * 8];
    }
#pragma unroll
    for (int i = 0; i < 4; ++i)
#pragma unroll
      for (int j = 0; j < 4; ++j)
        acc[i][j] = __builtin_amdgcn_mfma_f32_16x16x32_bf16(af[i], bfr[j],
                                                            acc[i][j], 0, 0, 0);
    __syncthreads();
  }
#pragma unroll
  for (int i = 0; i < 4; ++i)
#pragma unroll
    for (int j = 0; j < 4; ++j) {
      const int col = n0 + wn + j * 16 + l15;
      const float bv = bias[col];
#pragma unroll
      for (int r = 0; r < 4; ++r) {
        const int row = m0 + wm + i * 16 + quad * 4 + r;
        Out[(size_t)row * Hn + col] = f2bf(fmaxf(acc[i][j][r] + bv, 0.0f));
      }
    }
}

// Static mask block (exact path): compsT[j] = |vc|*sigmoid(-u(e_sp))
__device__ __forceinline__ void smask_block(
    const float* __restrict__ vc, const float* __restrict__ e_sp,
    const uint32_t* __restrict__ keys, ushort* __restrict__ compsT, int g) {
  uint32_t j = (uint32_t)g * 256 + threadIdx.x;  // j = d*C + c
  uint32_t c = j & (Cn - 1), d = j >> 9;
  uint32_t ridx = c * Dn + d;
  float e = e_sp[ridx];
  float u = 0.0f;
#pragma unroll 1
  for (int t = 0; t < 32; ++t) {
    uint32_t o0, o1;
    threefry2x32(keys[2 * t], keys[2 * t + 1], 0u, ridx, o0, o1);
    float n = bits_to_normal(o0 ^ o1);
    u = (u - 0.05f * (u + e)) + 0.1f * n;
  }
  float gt = 1.0f / (1.0f + __expf(u));
  compsT[j] = f2bf(fabsf(vc[ridx]) * gt);
}

// Z block: 4 elements/thread, source-interleaved threefry (forces 4-way ILP),
// f32x2-packed erfinv poly + chain (v_pk_fma_f32). Tail capped at w=5
// (error sub-bf16-visible).  Z = sum 0.95^(31-t) * 0.1*sqrt2 * px_t.
__device__ __forceinline__ void zdyn_block(
    const uint32_t* __restrict__ keys, ushort* __restrict__ Z, uint32_t rb) {
  const uint32_t j0 = (rb * 256u + threadIdx.x) * 4u;
  f32x2 zA = {0.0f, 0.0f}, zB = {0.0f, 0.0f};
  const f32x2 C95 = {0.95f, 0.95f};
  const f32x2 CNS = {0.14142135f, 0.14142135f};  // 0.1 * sqrt(2)
#pragma unroll 2
  for (int t = 0; t < 32; ++t) {
    const uint32_t K0 = keys[2 * t], K1 = keys[2 * t + 1];
    const uint32_t KX = K0 ^ K1 ^ 0x1BD11BDAu;
    uint32_t a0 = K0, a1 = K0, a2 = K0, a3 = K0;
    uint32_t b0 = K1 + j0, b1 = K1 + j0 + 1u, b2 = K1 + j0 + 2u,
             b3 = K1 + j0 + 3u;
#define R4(r)                                                            \
    a0 += b0; a1 += b1; a2 += b2; a3 += b3;                              \
    b0 = rotl32(b0, r); b1 = rotl32(b1, r);                              \
    b2 = rotl32(b2, r); b3 = rotl32(b3, r);                              \
    b0 ^= a0; b1 ^= a1; b2 ^= a2; b3 ^= a3;
#define I4(p, q)                                                         \
    a0 += (p); a1 += (p); a2 += (p); a3 += (p);                          \
    b0 += (q); b1 += (q); b2 += (q); b3 += (q);
    R4(13) R4(15) R4(26) R4(6)  I4(K1, KX + 1u)
    R4(17) R4(29) R4(16) R4(24) I4(KX, K0 + 2u)
    R4(13) R4(15) R4(26) R4(6)  I4(K0, K1 + 3u)
    R4(17) R4(29) R4(16) R4(24) I4(K1, KX + 4u)
    R4(13) R4(15) R4(26) R4(6)  I4(KX, K0 + 5u)
#undef R4
#undef I4
    float X0, W0, X1, W1, X2, W2, X3, W3;
#define WPREP(s, xo, wo) {                                               \
    float f_ = __uint_as_float(((s) >> 9) | 0x3f800000u) - 1.0f;         \
    xo = f_ * 2.0f - 0x1.fffffep-1f;                                     \
    wo = fminf(-__logf(fmaf(-xo, xo, 1.0f)), 5.0f) - 2.5f; }
    WPREP(a0 ^ b0, X0, W0)
    WPREP(a1 ^ b1, X1, W1)
    WPREP(a2 ^ b2, X2, W2)
    WPREP(a3 ^ b3, X3, W3)
#undef WPREP
    f32x2 xA = {X0, X1}, wA = {W0, W1};
    f32x2 xB = {X2, X3}, wB = {W2, W3};
#define POLY(w, x, zacc) {                                               \
    f32x2 p_ = (f32x2){2.81022636e-08f, 2.81022636e-08f};                \
    p_ = p_ * (w) + (f32x2){3.43273939e-07f, 3.43273939e-07f};           \
    p_ = p_ * (w) + (f32x2){-3.5233877e-06f, -3.5233877e-06f};           \
    p_ = p_ * (w) + (f32x2){-4.39150654e-06f, -4.39150654e-06f};         \
    p_ = p_ * (w) + (f32x2){0.00021858087f, 0.00021858087f};             \
    p_ = p_ * (w) + (f32x2){-0.00125372503f, -0.00125372503f};           \
    p_ = p_ * (w) + (f32x2){-0.00417768164f, -0.00417768164f};           \
    p_ = p_ * (w) + (f32x2){0.246640727f, 0.246640727f};                 \
    p_ = p_ * (w) + (f32x2){1.50140941f, 1.50140941f};                   \
    zacc = C95 * (zacc) + (p_ * (x)) * CNS; }
    POLY(wA, xA, zA)
    POLY(wB, xB, zB)
#undef POLY
  }
  *(ushort4*)(Z + j0) =
      make_ushort4(f2bf(zA.x), f2bf(zA.y), f2bf(zB.x), f2bf(zB.y));
}

// K1: 11264 blocks = 1024 groups x 11: pos 0=G1, 1=G3, 2=SMASK, 3..10=Zdyn
__global__ __launch_bounds__(256) void k_mega(
    const ushort* __restrict__ x_bf,
    const ushort* __restrict__ W1eT, const float* __restrict__ b1e,
    ushort* __restrict__ h,
    const ushort* __restrict__ W1rT, const float* __restrict__ b1r,
    ushort* __restrict__ hr,
    const float* __restrict__ vc, const float* __restrict__ e_sp,
    const uint32_t* __restrict__ keys, ushort* __restrict__ compsT,
    ushort* __restrict__ Zdyn) {
  __shared__ ushort As[128][40];
  __shared__ ushort Bs[128][40];
  const uint32_t bx = blockIdx.x;
  const uint32_t group = bx / 11u, pos = bx % 11u;
  if (pos == 0u)
    gemm_tile_bf(x_bf, W1eT, b1e, h, (int)group, As, Bs);
  else if (pos == 1u)
    gemm_tile_bf(x_bf, W1rT, b1r, hr, (int)group, As, Bs);
  else if (pos == 2u)
    smask_block(vc, e_sp, keys, compsT, (int)group);
  else
    zdyn_block(keys + 64, Zdyn, group * 8u + (pos - 3u));
}

// ---------------------------------------------------------------------------
// K2: double GEMM + gate (verified round 7).
// ---------------------------------------------------------------------------
__global__ __launch_bounds__(256) void k_dgemm(
    const ushort* __restrict__ h, const ushort* __restrict__ W2eT,
    const float* __restrict__ b2e,
    const ushort* __restrict__ hr, const ushort* __restrict__ W2rT,
    const float* __restrict__ b2r,
    ushort* __restrict__ Zconc) {
  __shared__ ushort As[128][40];
  __shared__ ushort Bs[128][40];
  const int t = threadIdx.x;
  const int m0 = blockIdx.y * 128, n0 = blockIdx.x * 128;
  const int srow = t >> 1, skb = (t & 1) << 4;
  const int wave = t >> 6, lane = t & 63;
  const int wm = (wave >> 1) << 6, wn = (wave & 1) << 6;
  const int quad = lane >> 4, l15 = lane & 15;

  const ushort* Ap = h    + (size_t)(m0 + srow) * Hn + skb;
  const ushort* Bp = W2eT + (size_t)(n0 + srow) * Hn + skb;
  f32x4 acc[4][4] = {};
  for (int k0 = 0; k0 < Hn; k0 += 32) {
    uint4 a0 = *(const uint4*)(Ap + k0);
    uint4 a1 = *(const uint4*)(Ap + k0 + 8);
    uint4 b0 = *(const uint4*)(Bp + k0);
    uint4 b1 = *(const uint4*)(Bp + k0 + 8);
    *(uint4*)&As[srow][skb] = a0; *(uint4*)&As[srow][skb + 8] = a1;
    *(uint4*)&Bs[srow][skb] = b0; *(uint4*)&Bs[srow][skb + 8] = b1;
    __syncthreads();
    bf16x8 af[4], bfr[4];
#pragma unroll
    for (int i = 0; i < 4; ++i) {
      af[i] = *(const bf16x8*)&As[wm + i * 16 + l15][quad * 8];
      bfr[i] = *(const bf16x8*)&Bs[wn + i * 16 + l15][quad * 8];
    }
#pragma unroll
    for (int i = 0; i < 4; ++i)
#pragma unroll
      for (int j = 0; j < 4; ++j)
        acc[i][j] = __builtin_amdgcn_mfma_f32_16x16x32_bf16(af[i], bfr[j],
                                                            acc[i][j], 0, 0, 0);
    __syncthreads();
  }
  float g[4][4][4];
#pragma unroll
  for (int i = 0; i < 4; ++i)
#pragma unroll
    for (int j = 0; j < 4; ++j) {
      const int col = n0 + wn + j * 16 + l15;
      const float bv = b2e[col];
#pragma unroll
      for (int r = 0; r < 4; ++r) {
        const int row = m0 + wm + i * 16 + quad * 4 + r;
        float e = acc[i][j][r] + bv;
        float z = b2f(Zconc[(size_t)row * Cn + col]);
        g[i][j][r] = 1.0f / (1.0f + __expf(z - A32 * e));
        acc[i][j][r] = 0.0f;
      }
    }
  Ap = hr   + (size_t)(m0 + srow) * Hn + skb;
  Bp = W2rT + (size_t)(n0 + srow) * Hn + skb;
  for (int k0 = 0; k0 < Hn; k0 += 32) {
    uint4 a0 = *(const uint4*)(Ap + k0);
    uint4 a1 = *(const uint4*)(Ap + k0 + 8);
    uint4 b0 = *(const uint4*)(Bp + k0);
    uint4 b1 = *(const uint4*)(Bp + k0 + 8);
    __syncthreads();
    *(uint4*)&As[srow][skb] = a0; *(uint4*)&As[srow][skb + 8] = a1;
    *(uint4*)&Bs[srow][skb] = b0; *(uint4*)&Bs[srow][skb + 8] = b1;
    __syncthreads();
    bf16x8 af[4], bfr[4];
#pragma unroll
    for (int i = 0; i < 4; ++i) {
      af[i] = *(const bf16x8*)&As[wm + i * 16 + l15][quad * 8];
      bfr[i] = *(const bf16x8*)&Bs[wn + i * 16 + l15][quad * 8];
    }
#pragma unroll
    for (int i = 0; i < 4; ++i)
#pragma unroll
      for (int j = 0; j < 4; ++j)
        acc[i][j] = __builtin_amdgcn_mfma_f32_16x16x32_bf16(af[i], bfr[j],
                                                            acc[i][j], 0, 0, 0);
  }
#pragma unroll
  for (int i = 0; i < 4; ++i)
#pragma unroll
    for (int j = 0; j < 4; ++j) {
      const int col = n0 + wn + j * 16 + l15;
      const float bv = b2r[col];
#pragma unroll
      for (int r = 0; r < 4; ++r) {
        const int row = m0 + wm + i * 16 + quad * 4 + r;
        Zconc[(size_t)row * Cn + col] = f2bf((acc[i][j][r] + bv) * g[i][j][r]);
      }
    }
}

// ---------------------------------------------------------------------------
// K3: out = conc @ comps
// ---------------------------------------------------------------------------
__global__ __launch_bounds__(256) void k_gemm_out(
    const ushort* __restrict__ A, const ushort* __restrict__ WT,
    float* __restrict__ Out) {
  __shared__ ushort As[128][40];
  __shared__ ushort Bs[128][40];
  const int t = threadIdx.x;
  const int m0 = blockIdx.y * 128, n0 = blockIdx.x * 128;
  const int srow = t >> 1, skb = (t & 1) << 4;
  const ushort* Ap = A  + (size_t)(m0 + srow) * Cn + skb;
  const ushort* Bp = WT + (size_t)(n0 + srow) * Cn + skb;
  const int wave = t >> 6, lane = t & 63;
  const int wm = (wave >> 1) << 6, wn = (wave & 1) << 6;
  const int quad = lane >> 4, l15 = lane & 15;

  f32x4 acc[4][4] = {};
  for (int k0 = 0; k0 < Cn; k0 += 32) {
    uint4 a0 = *(const uint4*)(Ap + k0);
    uint4 a1 = *(const uint4*)(Ap + k0 + 8);
    uint4 b0 = *(const uint4*)(Bp + k0);
    uint4 b1 = *(const uint4*)(Bp + k0 + 8);
    *(uint4*)&As[srow][skb] = a0; *(uint4*)&As[srow][skb + 8] = a1;
    *(uint4*)&Bs[srow][skb] = b0; *(uint4*)&Bs[srow][skb + 8] = b1;
    __syncthreads();
    bf16x8 af[4], bfr[4];
#pragma unroll
    for (int i = 0; i < 4; ++i) {
      af[i] = *(const bf16x8*)&As[wm + i * 16 + l15][quad * 8];
      bfr[i] = *(const bf16x8*)&Bs[wn + i * 16 + l15][quad * 8];
    }
#pragma unroll
    for (int i = 0; i < 4; ++i)
#pragma unroll
      for (int j = 0; j < 4; ++j)
        acc[i][j] = __builtin_amdgcn_mfma_f32_16x16x32_bf16(af[i], bfr[j],
                                                            acc[i][j], 0, 0, 0);
    __syncthreads();
  }
#pragma unroll
  for (int i = 0; i < 4; ++i)
#pragma unroll
    for (int j = 0; j < 4; ++j) {
      const int col = n0 + wn + j * 16 + l15;
#pragma unroll
      for (int r = 0; r < 4; ++r) {
        const int row = m0 + wm + i * 16 + quad * 4 + r;
        Out[(size_t)row * Dn + col] = acc[i][j][r];
      }
    }
}

// ---------------------------------------------------------------------------
extern "C" void kernel_launch(void* const* d_in, const int* in_sizes, int n_in,
                              void* d_out, int out_size, void* d_ws, size_t ws_size,
                              hipStream_t stream) {
  const float* x    = (const float*)d_in[0];
  const float* vc   = (const float*)d_in[1];
  const float* e_sp = (const float*)d_in[2];
  const float* W1e  = (const float*)d_in[3];
  const float* b1e  = (const float*)d_in[4];
  const float* W2e  = (const float*)d_in[5];
  const float* b2e  = (const float*)d_in[6];
  const float* W1r  = (const float*)d_in[7];
  const float* b1r  = (const float*)d_in[8];
  const float* W2r  = (const float*)d_in[9];
  const float* b2r  = (const float*)d_in[10];
  float* out = (float*)d_out;

  // Workspace (88 MiB high-water, as round 7):
  //   0       keys (512 B)
  //   4096    W1eT | +1M W2eT | +2M W1rT | +3M W2rT  (bf16 transposed)
  //   +4M     compsT [D][C] bf16 (0.5 MiB)
  //   8M      Zdyn [B][C] bf16 (16 MiB) -> aliased as conc after K2
  //   24M     h  [B][H] bf16 (32 MiB)
  //   56M     hr [B][H] bf16 (32 MiB)
  // x_bf (16 MiB) lives in d_out (32 MiB, dead until K3 overwrites it).
  char* ws = (char*)d_ws;
  uint32_t* keys = (uint32_t*)ws;
  ushort* W1eT   = (ushort*)(ws + (1u << 12));
  ushort* W2eT   = (ushort*)(ws + (1u << 12) + (1u << 20));
  ushort* W1rT   = (ushort*)(ws + (1u << 12) + (2u << 20));
  ushort* W2rT   = (ushort*)(ws + (1u << 12) + (3u << 20));
  ushort* compsT = (ushort*)(ws + (1u << 12) + (4u << 20));
  ushort* Zdyn   = (ushort*)(ws + (8u << 20));   // then conc
  ushort* h_bf   = (ushort*)(ws + (24u << 20));
  ushort* hr_bf  = (ushort*)(ws + (56u << 20));
  ushort* x_bf   = (ushort*)d_out;               // scratch until K3

  // 1. keys + conversions
  k_setup_keys<<<1, 64, 0, stream>>>(keys);
  k_cvt_x<<<(Bn * Dn / 4) / 256, 256, 0, stream>>>(x, x_bf);
  k_transpose_cvt<<<(Dn * Hn) / 256, 256, 0, stream>>>(W1e, W1eT, Hn, Dn);
  k_transpose_cvt<<<(Hn * Cn) / 256, 256, 0, stream>>>(W2e, W2eT, Cn, Hn);
  k_transpose_cvt<<<(Dn * Hn) / 256, 256, 0, stream>>>(W1r, W1rT, Hn, Dn);
  k_transpose_cvt<<<(Hn * Cn) / 256, 256, 0, stream>>>(W2r, W2rT, Cn, Hn);
  // 2. mega-kernel: G1(h) + G3(hr) + static mask + Zdyn, co-scheduled
  k_mega<<<11264, 256, 0, stream>>>(x_bf, W1eT, b1e, h_bf, W1rT, b1r, hr_bf,
                                    vc, e_sp, keys, compsT, Zdyn);
  // 3. double GEMM: e -> gate -> conc (in-place over Zdyn)
  k_dgemm<<<dim3(Cn / 128, Bn / 128), 256, 0, stream>>>(
      h_bf, W2eT, b2e, hr_bf, W2rT, b2r, Zdyn);
  // 4. out = conc @ comps
  k_gemm_out<<<dim3(Dn / 128, Bn / 128), 256, 0, stream>>>(Zdyn, compsT, out);
}